// Round 5
// baseline (346.024 us; speedup 1.0000x reference)
//
#include <hip/hip_runtime.h>
#include <hip/hip_bf16.h>
#include <stdint.h>

typedef unsigned short u16;
typedef unsigned int u32;
typedef __attribute__((ext_vector_type(8))) short short8;  // 8 x bf16 (4 VGPRs)
typedef __attribute__((ext_vector_type(4))) float f32x4;

#define DEV __device__ __forceinline__

constexpr int S = 8192;
constexpr int DIM = 1280;
constexpr int H = 16;
constexpr int DH = 80;
constexpr int LSEG = 1024;      // uniform segment length (cu_seqlens = arange*1024)
constexpr int QKVN = 3 * DIM;   // 3840
// 80^-0.5 * log2(e): scores then feed exp2 directly (softmax invariant)
constexpr float SCALE = 0.11180339887498949f * 1.4426950408889634f;

DEV u16 f2bf(float f) {
  u32 u = __float_as_uint(f);
  return (u16)((u + 0x7FFFu + ((u >> 16) & 1u)) >> 16);  // round-to-nearest-even
}
DEV float bf2f(u16 h) { return __uint_as_float(((u32)h) << 16); }
DEV u32 pkbf(float a, float b) {       // v_cvt_pk_bf16_f32
  __hip_bfloat162 t = __float22bfloat162_rn(float2{a, b});
  u32 r; __builtin_memcpy(&r, &t, 4); return r;
}

DEV void glds16(const void* g, void* l) {
  __builtin_amdgcn_global_load_lds((__attribute__((address_space(1))) void*)g,
                                   (__attribute__((address_space(3))) void*)l,
                                   16, 0, 0);
}
DEV f32x4 mfma16(short8 a, short8 b, f32x4 c) {
  return __builtin_amdgcn_mfma_f32_16x16x32_bf16(a, b, c, 0, 0, 0);
}

// ---------- fp32 -> bf16 conversion of X, qkv_w, proj_w ----------
__global__ __launch_bounds__(256) void cvt_kernel(
    const float* __restrict__ X, const float* __restrict__ Wq,
    const float* __restrict__ Wp, u16* __restrict__ Xb,
    u16* __restrict__ Wqb, u16* __restrict__ Wpb) {
  size_t i = ((size_t)blockIdx.x * 256 + threadIdx.x) * 4;
  const size_t n1 = (size_t)S * DIM;      // 10485760
  const size_t n2 = (size_t)QKVN * DIM;   // 4915200
  const size_t n3 = (size_t)DIM * DIM;    // 1638400
  const float* src; u16* dst; size_t off;
  if (i < n1)                { src = X;  dst = Xb;  off = i; }
  else if (i < n1 + n2)      { src = Wq; dst = Wqb; off = i - n1; }
  else if (i < n1 + n2 + n3) { src = Wp; dst = Wpb; off = i - n1 - n2; }
  else return;
  float4 v = *(const float4*)(src + off);
  ushort4 r;
  r.x = f2bf(v.x); r.y = f2bf(v.y); r.z = f2bf(v.z); r.w = f2bf(v.w);
  *(ushort4*)(dst + off) = r;
}

// ---------- RoPE v2 (vectorized): QKV[s][3840] -> Qp[s][h][96], Kp[s][h][96] ----------
__global__ __launch_bounds__(256) void rope_kernel(
    const u16* __restrict__ QKV, const float* __restrict__ cosp,
    const float* __restrict__ sinp, u16* __restrict__ Qp, u16* __restrict__ Kp) {
  int idx = blockIdx.x * 256 + threadIdx.x;   // over S*H*5 exactly
  int c = idx % 5;
  int sh = idx / 5;
  int s = sh >> 4, h = sh & 15;
  const size_t gbase = (size_t)s * QKVN + h * DH + c * 8;
  const size_t pbase = (size_t)sh * 96 + c * 8;
  short8 q0 = *(const short8*)&QKV[gbase];
  short8 q1 = *(const short8*)&QKV[gbase + 40];
  short8 k0 = *(const short8*)&QKV[gbase + DIM];
  short8 k1 = *(const short8*)&QKV[gbase + DIM + 40];
  float4 ca0 = *(const float4*)&cosp[s * DH + c * 8];
  float4 ca1 = *(const float4*)&cosp[s * DH + c * 8 + 4];
  float4 cb0 = *(const float4*)&cosp[s * DH + c * 8 + 40];
  float4 cb1 = *(const float4*)&cosp[s * DH + c * 8 + 44];
  float4 sa0 = *(const float4*)&sinp[s * DH + c * 8];
  float4 sa1 = *(const float4*)&sinp[s * DH + c * 8 + 4];
  float4 sb0 = *(const float4*)&sinp[s * DH + c * 8 + 40];
  float4 sb1 = *(const float4*)&sinp[s * DH + c * 8 + 44];
  float ca[8] = {ca0.x, ca0.y, ca0.z, ca0.w, ca1.x, ca1.y, ca1.z, ca1.w};
  float cb[8] = {cb0.x, cb0.y, cb0.z, cb0.w, cb1.x, cb1.y, cb1.z, cb1.w};
  float sa[8] = {sa0.x, sa0.y, sa0.z, sa0.w, sa1.x, sa1.y, sa1.z, sa1.w};
  float sb[8] = {sb0.x, sb0.y, sb0.z, sb0.w, sb1.x, sb1.y, sb1.z, sb1.w};
  short8 qo0, qo1, ko0, ko1;
#pragma unroll
  for (int j = 0; j < 8; j++) {
    float qa = bf2f((u16)q0[j]), qb = bf2f((u16)q1[j]);
    float ka = bf2f((u16)k0[j]), kb = bf2f((u16)k1[j]);
    qo0[j] = (short)f2bf((qa * ca[j] - qb * sa[j]) * SCALE);
    qo1[j] = (short)f2bf((qb * cb[j] + qa * sb[j]) * SCALE);
    ko0[j] = (short)f2bf(ka * ca[j] - kb * sa[j]);
    ko1[j] = (short)f2bf(kb * cb[j] + ka * sb[j]);
  }
  *(short8*)&Qp[pbase]      = qo0;
  *(short8*)&Qp[pbase + 40] = qo1;
  *(short8*)&Kp[pbase]      = ko0;
  *(short8*)&Kp[pbase + 40] = ko1;
  if (c == 0) {                          // zero pads d=80..95
    short8 z = {};
    *(short8*)&Qp[pbase + 80] = z; *(short8*)&Qp[pbase + 88] = z;
    *(short8*)&Kp[pbase + 80] = z; *(short8*)&Kp[pbase + 88] = z;
  }
}

// ---------- V transpose + per-64 permute ----------
__global__ __launch_bounds__(256) void vtrans_kernel(
    const u16* __restrict__ QKV, u16* __restrict__ Vt) {
  __shared__ u16 Ls[64 * 88];             // 64 rows x 80 d, stride 88 (16B-aligned)
  const int s0 = blockIdx.x * 64, h = blockIdx.y;
  const int tid = threadIdx.x;
  for (int cc = tid; cc < 640; cc += 256) {   // 64 rows x 10 chunks of 8 elems
    int row = cc / 10, c = cc % 10;
    short8 v = *(const short8*)&QKV[(size_t)(s0 + row) * QKVN + 2 * DIM + h * 80 + c * 8];
    *(short8*)&Ls[row * 88 + c * 8] = v;
  }
  __syncthreads();
  for (int cc = tid; cc < 640; cc += 256) {   // 80 d-rows x 8 chunks of 8 out-pos
    int d = cc / 8, sc = cc % 8;
    u16 tmp[8];
#pragma unroll
    for (int j = 0; j < 8; j++) {
      int op = sc * 8 + j;
      int key = ((op & 3) << 4) + (op >> 2);  // inverse of pp()
      tmp[j] = Ls[key * 88 + d];
    }
    *(short8*)&Vt[(size_t)(h * 80 + d) * S + s0 + sc * 8] = *(short8*)tmp;
  }
}

// ---------- GEMM v8: 256x256, BK=64, SINGLE-BARRIER K-tile (whole tile one window) -
// Model (R4): per K-tile per SIMD, MFMA = 2480 cyc; per CU, LDS reads ~2300 cyc.
// v4-v7's barrier-per-phase lockstep globally SERIALIZED these (5160 cyc/tile
// observed = 2480+2300+overhead).  v8: ONE barrier pair per K-tile; the whole
// tile's {8 glds staging, 24 ds_read_b128, 64 MFMA} share one window so the
// compiler interleaves reads under MFMAs (its fine-grained lgkmcnt is
// near-optimal absent barriers).  Sync collapses to the tile boundary:
//  - WAR: tile t stages into buf b^1, read last in tile t-1's body, sealed by
//    the boundary barrier (reads are consumed by MFMAs before the wave arrives).
//  - RAW: tile t reads buf b, staged at the TOP of t-1 -> each wave's vmcnt(0)
//    at the END of t-1 drains loads issued ~2500 cyc earlier (free), then the
//    barrier publishes them.  No counted vmcnt needed; no lgkm asm at all.
template <bool OUT_F32>
__global__ __launch_bounds__(512, 2) void gemm_bt(
    const u16* __restrict__ A, const u16* __restrict__ B,
    const float* __restrict__ bias, void* __restrict__ C, int K, int N) {
  __shared__ u16 As[2][2][8192];   // [dbuf][half][128*64]
  __shared__ u16 Bs[2][2][8192];
  const int ntn = N >> 8;                       // n-tiles
  const int q = gridDim.x >> 3;                 // bijective XCD swizzle (nwg%8==0)
  const int widx = (blockIdx.x & 7) * q + (blockIdx.x >> 3);
  const int m0 = (widx / ntn) << 8;             // n-fastest: XCD works 1024-row A slab
  const int n0 = (widx % ntn) << 8;
  const int tid = threadIdx.x;
  const int w = tid >> 6, lane = tid & 63;
  const int quad = lane >> 4, l16 = lane & 15;
  const int wm = w >> 2, wn = w & 3;            // wave grid 2 x 4

  // staging: per half-tile (128 rows x 64 k) each wave does 2 glds16 (8 rows each).
  // LDS linear in write order; global source pre-swizzled: col-chunk = (lane&7)^(lane>>3)
  const int rowoff = w * 8 + (lane >> 3);
  const int coloff = ((lane & 7) ^ (lane >> 3)) * 8;
  const u16* pa0 = A + (size_t)(m0 + rowoff) * K + coloff;         // A half0 (rows 0..127)
  const u16* pa1 = A + (size_t)(m0 + 128 + rowoff) * K + coloff;   // A half1
  const u16* pb0 = B + (size_t)(n0 + rowoff) * K + coloff;
  const u16* pb1 = B + (size_t)(n0 + 128 + rowoff) * K + coloff;
  const size_t j64 = (size_t)64 * K;

#define STG(P, DST, kk) do { \
    glds16((P) + (kk), &(DST)[w * 512]); \
    glds16((P) + j64 + (kk), &(DST)[4096 + w * 512]); } while (0)
#define BARR()  __builtin_amdgcn_s_barrier()

  // frag read addressing (row&7 == l16&7 for all frag rows)
  const int aro = (wm * 16 + l16) * 64;                 // + i*32*64
  const int bro = (wn * 16 + l16) * 64;                 // + j*64*64
  const int kc0 = ((quad) ^ (l16 & 7)) * 8;             // ks=0 swizzled chunk
  const int kc1 = ((4 + quad) ^ (l16 & 7)) * 8;         // ks=1

  f32x4 acc[8][4] = {};
  short8 af[4][2], bf0[2][2], bf1[2][2];
  const int NT = K >> 6;   // K-tiles (20 for K=1280)

  // prologue: stage tile0 into buf0; drain; publish
  STG(pa0, As[0][0], 0); STG(pb0, Bs[0][0], 0);
  STG(pb1, Bs[0][1], 0); STG(pa1, As[0][1], 0);
  asm volatile("s_waitcnt vmcnt(0)");
  BARR();

  for (int t = 0; t < NT; ++t) {
    const int b = t & 1;
    const int kk = (t + 1) << 6;
    // stage tile t+1 into buf b^1 (WAR-safe: b^1's readers were tile t-1, sealed
    // by the boundary barrier).  Issued first so the compiler keeps the vmem
    // convoy at the top of the window.
    if (t + 1 < NT) {
      STG(pa0, As[b ^ 1][0], kk); STG(pb0, Bs[b ^ 1][0], kk);
      STG(pb1, Bs[b ^ 1][1], kk); STG(pa1, As[b ^ 1][1], kk);
    }
    // body: 24 ds_read_b128 + 64 MFMA in one window; no barriers, no waitcnt asm —
    // compiler hoists reads and interleaves MFMAs with fine-grained lgkmcnt.
#pragma unroll
    for (int i = 0; i < 4; i++) {
      af[i][0] = *(const short8*)&As[b][0][aro + i * 2048 + kc0];
      af[i][1] = *(const short8*)&As[b][0][aro + i * 2048 + kc1];
    }
#pragma unroll
    for (int jj = 0; jj < 2; jj++) {
      bf0[jj][0] = *(const short8*)&Bs[b][0][bro + jj * 4096 + kc0];
      bf0[jj][1] = *(const short8*)&Bs[b][0][bro + jj * 4096 + kc1];
    }
    __builtin_amdgcn_s_setprio(1);
#pragma unroll
    for (int ks = 0; ks < 2; ks++)
#pragma unroll
      for (int i = 0; i < 4; i++)
#pragma unroll
        for (int jj = 0; jj < 2; jj++)
          acc[i][jj] = mfma16(af[i][ks], bf0[jj][ks], acc[i][jj]);
    __builtin_amdgcn_s_setprio(0);
#pragma unroll
    for (int jj = 0; jj < 2; jj++) {
      bf1[jj][0] = *(const short8*)&Bs[b][1][bro + jj * 4096 + kc0];
      bf1[jj][1] = *(const short8*)&Bs[b][1][bro + jj * 4096 + kc1];
    }
    __builtin_amdgcn_s_setprio(1);
#pragma unroll
    for (int ks = 0; ks < 2; ks++)
#pragma unroll
      for (int i = 0; i < 4; i++)
#pragma unroll
        for (int jj = 0; jj < 2; jj++)
          acc[i][2 + jj] = mfma16(af[i][ks], bf1[jj][ks], acc[i][2 + jj]);
    __builtin_amdgcn_s_setprio(0);
#pragma unroll
    for (int i = 0; i < 4; i++) {
      af[i][0] = *(const short8*)&As[b][1][aro + i * 2048 + kc0];
      af[i][1] = *(const short8*)&As[b][1][aro + i * 2048 + kc1];
    }
    __builtin_amdgcn_s_setprio(1);
#pragma unroll
    for (int ks = 0; ks < 2; ks++)
#pragma unroll
      for (int i = 0; i < 4; i++)
#pragma unroll
        for (int jj = 0; jj < 2; jj++)
          acc[4 + i][jj] = mfma16(af[i][ks], bf0[jj][ks], acc[4 + i][jj]);
#pragma unroll
    for (int ks = 0; ks < 2; ks++)
#pragma unroll
      for (int i = 0; i < 4; i++)
#pragma unroll
        for (int jj = 0; jj < 2; jj++)
          acc[4 + i][2 + jj] = mfma16(af[i][ks], bf1[jj][ks], acc[4 + i][2 + jj]);
    __builtin_amdgcn_s_setprio(0);
    // tile boundary: drain this tile's stages (issued ~full tile ago -> cheap),
    // publish to all waves; also seals this tile's reads before next stage.
    asm volatile("s_waitcnt vmcnt(0)");
    BARR();
  }
#undef STG
#undef BARR
  // epilogue: C row = m0 + mf*32 + wm*16 + quad*4 + r; col = n0 + nf*64 + wn*16 + l16
#pragma unroll
  for (int nf = 0; nf < 4; nf++) {
    int col = n0 + nf * 64 + wn * 16 + l16;
    float bv = bias[col];
#pragma unroll
    for (int mf = 0; mf < 8; mf++) {
#pragma unroll
      for (int r = 0; r < 4; r++) {
        int row = m0 + mf * 32 + wm * 16 + quad * 4 + r;
        float v = acc[mf][nf][r] + bv;
        if (OUT_F32) ((float*)C)[(size_t)row * N + col] = v;
        else         ((u16*)C)[(size_t)row * N + col] = f2bf(v);
      }
    }
  }
}

// ---------- flash attention v6: 64-key tiles, double-buffered single-barrier ----------
__global__ __launch_bounds__(256, 2) void attn_kernel(
    const u16* __restrict__ Qp, const u16* __restrict__ Kp,
    const u16* __restrict__ Vt, u16* __restrict__ O) {
  __shared__ u16 Ks[2][64 * 104];   // 26.6 KB
  __shared__ u16 Vs[2][86 * 72];    // 24.2 KB
  __shared__ u16 Ps[4][16 * 72];    //  9.2 KB, per-wave (reused across mt)
  const int bid = blockIdx.x;
  const int phi = bid & 7, qt = (bid >> 3) & 7, pj = bid >> 6;
  const int p = pj * 8 + phi;       // (g,h) pair; its 8 qt-blocks share XCD
  const int g = p >> 4, h = p & 15;
  const int tid = threadIdx.x;
  const int w = tid >> 6, lane = tid & 63;
  const int quad = lane >> 4, l16 = lane & 15;

  short8 aq[2][3];
  const size_t qbase = ((size_t)(g * LSEG + qt * 128 + w * 32 + l16)) * 1536 + h * 96;
#pragma unroll
  for (int mt = 0; mt < 2; mt++)
#pragma unroll
    for (int ks = 0; ks < 3; ks++)
      aq[mt][ks] = *(const short8*)&Qp[qbase + (size_t)mt * 16 * 1536 + ks * 32 + quad * 8];

  const u16* gp[7]; u16* lp0[7]; u16* lp1[7]; int stp[7]; bool act[7];
#pragma unroll
  for (int i = 0; i < 7; i++) {
    int c = w + 4 * i;
    act[i] = (c < 25);
    int cc = act[i] ? c : 0;
    if (cc < 13) {                      // K: LDS elem = key*104 + rc*8
      int idx = cc * 64 + lane;
      int key = idx / 13, rc = idx % 13;
      int col = rc * 8; if (col >= 96) col = 0;
      gp[i] = Kp + (size_t)(g * LSEG + key) * 1536 + h * 96 + col;
      stp[i] = 64 * 1536;
      lp0[i] = &Ks[0][cc * 512]; lp1[i] = &Ks[1][cc * 512];
    } else {                            // V: LDS elem = d*72 + rc*8
      int cv = cc - 13;
      int idx = cv * 64 + lane;
      int d = idx / 9, rc = idx % 9;
      int col = rc * 8; if (col >= 64) col = 0;
      if (d >= 80) d = 0;
      gp[i] = Vt + (size_t)(h * 80 + d) * S + g * LSEG + col;
      stp[i] = 64;
      lp0[i] = &Vs[0][cv * 512]; lp1[i] = &Vs[1][cv * 512];
    }
  }
#pragma unroll
  for (int i = 0; i < 7; i++)
    if (act[i]) { glds16(gp[i], lp0[i]); gp[i] += stp[i]; }

  f32x4 o[2][5] = {};
  float lr[2][4] = {};
  u16* psw = &Ps[w][0];

  for (int kb = 0; kb < LSEG / 64; kb++) {
    const int b = kb & 1;
    __syncthreads();                    // drains prefetch of buf b (hidden by prior compute)
    if (kb < LSEG / 64 - 1) {           // prefetch next tile into buf b^1
      if (b == 0) {
#pragma unroll
        for (int i = 0; i < 7; i++)
          if (act[i]) { glds16(gp[i], lp1[i]); gp[i] += stp[i]; }
      } else {
#pragma unroll
        for (int i = 0; i < 7; i++)
          if (act[i]) { glds16(gp[i], lp0[i]); gp[i] += stp[i]; }
      }
    }
    f32x4 s[2][4] = {};
#pragma unroll
    for (int ks = 0; ks < 3; ks++) {
      short8 bk[4];
#pragma unroll
      for (int nt = 0; nt < 4; nt++)
        bk[nt] = *(const short8*)&Ks[b][(nt * 16 + l16) * 104 + ks * 32 + quad * 8];
#pragma unroll
      for (int mt = 0; mt < 2; mt++)
#pragma unroll
        for (int nt = 0; nt < 4; nt++)
          s[mt][nt] = mfma16(aq[mt][ks], bk[nt], s[mt][nt]);
    }
    short8 vb[5][2];
#pragma unroll
    for (int t = 0; t < 5; t++)
#pragma unroll
      for (int u = 0; u < 2; u++)
        vb[t][u] = *(const short8*)&Vs[b][(t * 16 + l16) * 72 + u * 32 + quad * 8];
#pragma unroll
    for (int mt = 0; mt < 2; mt++) {
#pragma unroll
      for (int r = 0; r < 4; r++) {
        float p0 = __builtin_amdgcn_exp2f(s[mt][0][r]);
        float p1 = __builtin_amdgcn_exp2f(s[mt][1][r]);
        float p2 = __builtin_amdgcn_exp2f(s[mt][2][r]);
        float p3 = __builtin_amdgcn_exp2f(s[mt][3][r]);
        lr[mt][r] += (p0 + p1) + (p2 + p3);
        int row = quad * 4 + r;
        uint2 pk; pk.x = pkbf(p0, p1); pk.y = pkbf(p2, p3);
        *(uint2*)&psw[row * 72 + l16 * 4] = pk;   // permuted cols: pp = l16*4 + nt
      }
      short8 pa0 = *(const short8*)&psw[l16 * 72 + quad * 8];
      short8 pa1 = *(const short8*)&psw[l16 * 72 + 32 + quad * 8];
#pragma unroll
      for (int t = 0; t < 5; t++)
        o[mt][t] = mfma16(pa0, vb[t][0], o[mt][t]);
#pragma unroll
      for (int t = 0; t < 5; t++)
        o[mt][t] = mfma16(pa1, vb[t][1], o[mt][t]);
    }
  }
#pragma unroll
  for (int mt = 0; mt < 2; mt++)
#pragma unroll
    for (int r = 0; r < 4; r++) {
      float t = lr[mt][r];
#pragma unroll
      for (int off = 8; off >= 1; off >>= 1) t += __shfl_xor(t, off, 16);
      float inv = 1.f / t;
      int srow = g * LSEG + qt * 128 + w * 32 + mt * 16 + quad * 4 + r;
#pragma unroll
      for (int tt = 0; tt < 5; tt++)
        O[(size_t)srow * DIM + h * DH + tt * 16 + l16] = f2bf(o[mt][tt][r] * inv);
    }
}

extern "C" void kernel_launch(void* const* d_in, const int* in_sizes, int n_in,
                              void* d_out, int out_size, void* d_ws, size_t ws_size,
                              hipStream_t stream) {
  const float* X     = (const float*)d_in[0];
  const float* cosp  = (const float*)d_in[1];
  const float* sinp  = (const float*)d_in[2];
  const float* qkvw  = (const float*)d_in[3];
  const float* qkvb  = (const float*)d_in[4];
  const float* projw = (const float*)d_in[5];
  const float* projb = (const float*)d_in[6];
  float* out = (float*)d_out;

  // workspace layout (u16 elems), ~143 MB total with aliasing:
  u16* Xb   = (u16*)d_ws;                     // 10,485,760  (dead after QKV gemm)
  u16* Wqb  = Xb   + (size_t)S * DIM;         //  4,915,200  (dead after QKV gemm)
  u16* Wpb  = Wqb  + (size_t)QKVN * DIM;      //  1,638,400  (live till proj)
  u16* QKVb = Wpb  + (size_t)DIM * DIM;       // 31,457,280  (dead after rope+vtrans)
  u16* Kp   = QKVb + (size_t)S * QKVN;        // 12,582,912
  u16* Vt   = Kp   + (size_t)S * H * 96;      // 10,485,760
  u16* Qp   = Xb;                             // alias: 12,582,912 <= Xb+Wqb region
  u16* AOb  = QKVb;                           // alias: 10,485,760 <= QKVb region

  cvt_kernel<<<16640, 256, 0, stream>>>(X, qkvw, projw, Xb, Wqb, Wpb);
  gemm_bt<false><<<(S / 256) * (QKVN / 256), 512, 0, stream>>>(Xb, Wqb, qkvb, QKVb, DIM, QKVN);
  rope_kernel<<<(S * H * 5) / 256, 256, 0, stream>>>(QKVb, cosp, sinp, Qp, Kp);
  vtrans_kernel<<<dim3(S / 64, H), 256, 0, stream>>>(QKVb, Vt);
  attn_kernel<<<1024, 256, 0, stream>>>(Qp, Kp, Vt, AOb);
  gemm_bt<true><<<(S / 256) * (DIM / 256), 512, 0, stream>>>(AOb, Wpb, projb, out, DIM, DIM);
}

// Round 7
// 325.201 us; speedup vs baseline: 1.0640x; 1.0640x over previous
//
#include <hip/hip_runtime.h>
#include <hip/hip_bf16.h>
#include <stdint.h>

typedef unsigned short u16;
typedef unsigned int u32;
typedef __attribute__((ext_vector_type(8))) short short8;  // 8 x bf16 (4 VGPRs)
typedef __attribute__((ext_vector_type(4))) float f32x4;

#define DEV __device__ __forceinline__

constexpr int S = 8192;
constexpr int DIM = 1280;
constexpr int H = 16;
constexpr int DH = 80;
constexpr int LSEG = 1024;      // uniform segment length (cu_seqlens = arange*1024)
constexpr int QKVN = 3 * DIM;   // 3840
// 80^-0.5 * log2(e): scores then feed exp2 directly (softmax invariant)
constexpr float SCALE = 0.11180339887498949f * 1.4426950408889634f;

DEV u16 f2bf(float f) {
  u32 u = __float_as_uint(f);
  return (u16)((u + 0x7FFFu + ((u >> 16) & 1u)) >> 16);  // round-to-nearest-even
}
DEV float bf2f(u16 h) { return __uint_as_float(((u32)h) << 16); }
DEV u32 pkbf(float a, float b) {       // v_cvt_pk_bf16_f32
  __hip_bfloat162 t = __float22bfloat162_rn(float2{a, b});
  u32 r; __builtin_memcpy(&r, &t, 4); return r;
}

DEV void glds16(const void* g, void* l) {
  __builtin_amdgcn_global_load_lds((__attribute__((address_space(1))) void*)g,
                                   (__attribute__((address_space(3))) void*)l,
                                   16, 0, 0);
}
DEV f32x4 mfma16(short8 a, short8 b, f32x4 c) {
  return __builtin_amdgcn_mfma_f32_16x16x32_bf16(a, b, c, 0, 0, 0);
}

// ---------- fp32 -> bf16 conversion of X, qkv_w, proj_w ----------
__global__ __launch_bounds__(256) void cvt_kernel(
    const float* __restrict__ X, const float* __restrict__ Wq,
    const float* __restrict__ Wp, u16* __restrict__ Xb,
    u16* __restrict__ Wqb, u16* __restrict__ Wpb) {
  size_t i = ((size_t)blockIdx.x * 256 + threadIdx.x) * 4;
  const size_t n1 = (size_t)S * DIM;      // 10485760
  const size_t n2 = (size_t)QKVN * DIM;   // 4915200
  const size_t n3 = (size_t)DIM * DIM;    // 1638400
  const float* src; u16* dst; size_t off;
  if (i < n1)                { src = X;  dst = Xb;  off = i; }
  else if (i < n1 + n2)      { src = Wq; dst = Wqb; off = i - n1; }
  else if (i < n1 + n2 + n3) { src = Wp; dst = Wpb; off = i - n1 - n2; }
  else return;
  float4 v = *(const float4*)(src + off);
  ushort4 r;
  r.x = f2bf(v.x); r.y = f2bf(v.y); r.z = f2bf(v.z); r.w = f2bf(v.w);
  *(ushort4*)(dst + off) = r;
}

// ---------- RoPE v2 (vectorized): QKV[s][3840] -> Qp[s][h][96], Kp[s][h][96] ----------
__global__ __launch_bounds__(256) void rope_kernel(
    const u16* __restrict__ QKV, const float* __restrict__ cosp,
    const float* __restrict__ sinp, u16* __restrict__ Qp, u16* __restrict__ Kp) {
  int idx = blockIdx.x * 256 + threadIdx.x;   // over S*H*5 exactly
  int c = idx % 5;
  int sh = idx / 5;
  int s = sh >> 4, h = sh & 15;
  const size_t gbase = (size_t)s * QKVN + h * DH + c * 8;
  const size_t pbase = (size_t)sh * 96 + c * 8;
  short8 q0 = *(const short8*)&QKV[gbase];
  short8 q1 = *(const short8*)&QKV[gbase + 40];
  short8 k0 = *(const short8*)&QKV[gbase + DIM];
  short8 k1 = *(const short8*)&QKV[gbase + DIM + 40];
  float4 ca0 = *(const float4*)&cosp[s * DH + c * 8];
  float4 ca1 = *(const float4*)&cosp[s * DH + c * 8 + 4];
  float4 cb0 = *(const float4*)&cosp[s * DH + c * 8 + 40];
  float4 cb1 = *(const float4*)&cosp[s * DH + c * 8 + 44];
  float4 sa0 = *(const float4*)&sinp[s * DH + c * 8];
  float4 sa1 = *(const float4*)&sinp[s * DH + c * 8 + 4];
  float4 sb0 = *(const float4*)&sinp[s * DH + c * 8 + 40];
  float4 sb1 = *(const float4*)&sinp[s * DH + c * 8 + 44];
  float ca[8] = {ca0.x, ca0.y, ca0.z, ca0.w, ca1.x, ca1.y, ca1.z, ca1.w};
  float cb[8] = {cb0.x, cb0.y, cb0.z, cb0.w, cb1.x, cb1.y, cb1.z, cb1.w};
  float sa[8] = {sa0.x, sa0.y, sa0.z, sa0.w, sa1.x, sa1.y, sa1.z, sa1.w};
  float sb[8] = {sb0.x, sb0.y, sb0.z, sb0.w, sb1.x, sb1.y, sb1.z, sb1.w};
  short8 qo0, qo1, ko0, ko1;
#pragma unroll
  for (int j = 0; j < 8; j++) {
    float qa = bf2f((u16)q0[j]), qb = bf2f((u16)q1[j]);
    float ka = bf2f((u16)k0[j]), kb = bf2f((u16)k1[j]);
    qo0[j] = (short)f2bf((qa * ca[j] - qb * sa[j]) * SCALE);
    qo1[j] = (short)f2bf((qb * cb[j] + qa * sb[j]) * SCALE);
    ko0[j] = (short)f2bf(ka * ca[j] - kb * sa[j]);
    ko1[j] = (short)f2bf(kb * cb[j] + ka * sb[j]);
  }
  *(short8*)&Qp[pbase]      = qo0;
  *(short8*)&Qp[pbase + 40] = qo1;
  *(short8*)&Kp[pbase]      = ko0;
  *(short8*)&Kp[pbase + 40] = ko1;
  if (c == 0) {                          // zero pads d=80..95
    short8 z = {};
    *(short8*)&Qp[pbase + 80] = z; *(short8*)&Qp[pbase + 88] = z;
    *(short8*)&Kp[pbase + 80] = z; *(short8*)&Kp[pbase + 88] = z;
  }
}

// ---------- V transpose + per-64 permute ----------
__global__ __launch_bounds__(256) void vtrans_kernel(
    const u16* __restrict__ QKV, u16* __restrict__ Vt) {
  __shared__ u16 Ls[64 * 88];             // 64 rows x 80 d, stride 88 (16B-aligned)
  const int s0 = blockIdx.x * 64, h = blockIdx.y;
  const int tid = threadIdx.x;
  for (int cc = tid; cc < 640; cc += 256) {   // 64 rows x 10 chunks of 8 elems
    int row = cc / 10, c = cc % 10;
    short8 v = *(const short8*)&QKV[(size_t)(s0 + row) * QKVN + 2 * DIM + h * 80 + c * 8];
    *(short8*)&Ls[row * 88 + c * 8] = v;
  }
  __syncthreads();
  for (int cc = tid; cc < 640; cc += 256) {   // 80 d-rows x 8 chunks of 8 out-pos
    int d = cc / 8, sc = cc % 8;
    u16 tmp[8];
#pragma unroll
    for (int j = 0; j < 8; j++) {
      int op = sc * 8 + j;
      int key = ((op & 3) << 4) + (op >> 2);  // inverse of pp()
      tmp[j] = Ls[key * 88 + d];
    }
    *(short8*)&Vt[(size_t)(h * 80 + d) * S + s0 + sc * 8] = *(short8*)tmp;
  }
}

// ---------- GEMM v9: 3 phases / 2 barriers per K-tile, fully pipelined reads --------
// Proven v7 idiom (clobber-free waits, builtin barriers) + every ds_read issued in
// an earlier phase's MFMA shadow + redundant barriers deleted.
// Quadrants: q00(a0,b0) q01(a0,b1) q10(a1,b0) q11(a1,b1).
// PH-A: [read a0,b1 | stage h0(t+1) | lgkm(4): a0+prefetched-b0 ready | q00 |
//        vmcnt(4): Ah1(t) landed | BAR#1 publishes Ah1(t)]
// PH-B: [lgkm(0): b1 (drained under q00) | stage Bh1(t+1) | q01 with a1-reads
//        interleaved after each a0[i]'s last use (reg WAR orders them) |
//        stage Ah1(t+1) | lgkm(0): a1 (drained under q01) | q10 |
//        vmcnt(2): h0(t+1)+Bh1(t+1) landed | BAR#2 publishes them]
// PH-C: [prefetch b0(t+1) into bf0's own regs (dead after q10) | q11] — no barrier;
//        overlaps next PH-A.
// FIFO invariant entering PH-A(t): outstanding glds = [Ah1(t) x2].  Publication:
// a0,b1,b0next <- BAR#2(t-1) (vmcnt(2));  a1 <- BAR#1(t) (vmcnt(4)).  WAR: each
// STG targets buf b^1 whose readers finished before the barrier preceding it.
template <bool OUT_F32>
__global__ __launch_bounds__(512, 2) void gemm_bt(
    const u16* __restrict__ A, const u16* __restrict__ B,
    const float* __restrict__ bias, void* __restrict__ C, int K, int N) {
  __shared__ u16 As[2][2][8192];   // [dbuf][half][128*64]
  __shared__ u16 Bs[2][2][8192];
  const int ntn = N >> 8;                       // n-tiles
  const int q = gridDim.x >> 3;                 // bijective XCD swizzle (nwg%8==0)
  const int widx = (blockIdx.x & 7) * q + (blockIdx.x >> 3);
  const int m0 = (widx / ntn) << 8;             // n-fastest: XCD works 1024-row A slab
  const int n0 = (widx % ntn) << 8;
  const int tid = threadIdx.x;
  const int w = tid >> 6, lane = tid & 63;
  const int quad = lane >> 4, l16 = lane & 15;
  const int wm = w >> 2, wn = w & 3;            // wave grid 2 x 4

  // staging: per half-tile (128 rows x 64 k) each wave does 2 glds16 (8 rows each).
  // LDS linear in write order; global source pre-swizzled: col-chunk = (lane&7)^(lane>>3)
  const int rowoff = w * 8 + (lane >> 3);
  const int coloff = ((lane & 7) ^ (lane >> 3)) * 8;
  const u16* pa0 = A + (size_t)(m0 + rowoff) * K + coloff;         // A half0 (rows 0..127)
  const u16* pa1 = A + (size_t)(m0 + 128 + rowoff) * K + coloff;   // A half1
  const u16* pb0 = B + (size_t)(n0 + rowoff) * K + coloff;
  const u16* pb1 = B + (size_t)(n0 + 128 + rowoff) * K + coloff;
  const size_t j64 = (size_t)64 * K;

#define STG(P, DST, kk) do { \
    glds16((P) + (kk), &(DST)[w * 512]); \
    glds16((P) + j64 + (kk), &(DST)[4096 + w * 512]); } while (0)
#define BARR()  __builtin_amdgcn_s_barrier()
#define SCHED0() __builtin_amdgcn_sched_barrier(0)

  // frag read addressing (row&7 == l16&7 for all frag rows)
  const int aro = (wm * 16 + l16) * 64;                 // + i*32*64
  const int bro = (wn * 16 + l16) * 64;                 // + j*64*64
  const int kc0 = ((quad) ^ (l16 & 7)) * 8;             // ks=0 swizzled chunk
  const int kc1 = ((4 + quad) ^ (l16 & 7)) * 8;         // ks=1

  f32x4 acc[8][4] = {};
  short8 af[4][2], bf0[2][2], bf1[2][2];
  const int NT = K >> 6;   // K-tiles (20 for K=1280)

  // prologue: stage tile0 [h0 x4, Bh1 x2, Ah1 x2]; drain h0+Bh1; publish; prefetch b0
  STG(pa0, As[0][0], 0); STG(pb0, Bs[0][0], 0);
  STG(pb1, Bs[0][1], 0);
  STG(pa1, As[0][1], 0);
  asm volatile("s_waitcnt vmcnt(2)");
  BARR();
#pragma unroll
  for (int jj = 0; jj < 2; jj++) {
    bf0[jj][0] = *(const short8*)&Bs[0][0][bro + jj * 4096 + kc0];
    bf0[jj][1] = *(const short8*)&Bs[0][0][bro + jj * 4096 + kc1];
  }
  // entering loop: outstanding glds = [Ah1(0) x2]; bf0 reads (4) in flight

  for (int t = 0; t < NT; ++t) {
    const int b = t & 1;
    const int kk = (t + 1) << 6;
    const bool pf = (t + 1 < NT);
    // ---- PH-A ----
#pragma unroll
    for (int i = 0; i < 4; i++) {
      af[i][0] = *(const short8*)&As[b][0][aro + i * 2048 + kc0];
      af[i][1] = *(const short8*)&As[b][0][aro + i * 2048 + kc1];
    }
#pragma unroll
    for (int jj = 0; jj < 2; jj++) {
      bf1[jj][0] = *(const short8*)&Bs[b][1][bro + jj * 4096 + kc0];
      bf1[jj][1] = *(const short8*)&Bs[b][1][bro + jj * 4096 + kc1];
    }
    if (pf) { STG(pa0, As[b ^ 1][0], kk); STG(pb0, Bs[b ^ 1][0], kk); }
    asm volatile("s_waitcnt lgkmcnt(4)");   // a0 + b0(prefetched) ready; b1 flying
    SCHED0();
    __builtin_amdgcn_s_setprio(1);
#pragma unroll
    for (int ks = 0; ks < 2; ks++)
#pragma unroll
      for (int i = 0; i < 4; i++)
#pragma unroll
        for (int jj = 0; jj < 2; jj++)
          acc[i][jj] = mfma16(af[i][ks], bf0[jj][ks], acc[i][jj]);
    __builtin_amdgcn_s_setprio(0);
    SCHED0();
    if (pf) asm volatile("s_waitcnt vmcnt(4)");   // Ah1(t) landed
    else    asm volatile("s_waitcnt vmcnt(0)");
    BARR();                                        // #1: publishes Ah1(t)
    // ---- PH-B ----
    asm volatile("s_waitcnt lgkmcnt(0)");   // b1 ready (drained under q00)
    SCHED0();
    if (pf) STG(pb1, Bs[b ^ 1][1], kk);
    __builtin_amdgcn_s_setprio(1);
#pragma unroll
    for (int i = 0; i < 4; i++) {
      // q01 MFMAs consuming a0[i], then overwrite af[i] with a1[i] (WAR orders read)
      acc[i][2] = mfma16(af[i][0], bf1[0][0], acc[i][2]);
      acc[i][3] = mfma16(af[i][0], bf1[1][0], acc[i][3]);
      acc[i][2] = mfma16(af[i][1], bf1[0][1], acc[i][2]);
      acc[i][3] = mfma16(af[i][1], bf1[1][1], acc[i][3]);
      af[i][0] = *(const short8*)&As[b][1][aro + i * 2048 + kc0];
      af[i][1] = *(const short8*)&As[b][1][aro + i * 2048 + kc1];
    }
    __builtin_amdgcn_s_setprio(0);
    if (pf) STG(pa1, As[b ^ 1][1], kk);
    asm volatile("s_waitcnt lgkmcnt(0)");   // a1 ready (drained under q01)
    SCHED0();
    __builtin_amdgcn_s_setprio(1);
#pragma unroll
    for (int ks = 0; ks < 2; ks++)
#pragma unroll
      for (int i = 0; i < 4; i++)
#pragma unroll
        for (int jj = 0; jj < 2; jj++)
          acc[4 + i][jj] = mfma16(af[i][ks], bf0[jj][ks], acc[4 + i][jj]);
    __builtin_amdgcn_s_setprio(0);
    SCHED0();
    if (pf) asm volatile("s_waitcnt vmcnt(2)");   // h0(t+1)+Bh1(t+1) landed
    else    asm volatile("s_waitcnt vmcnt(0)");
    BARR();                                        // #2: publishes h0/Bh1(t+1)
    // ---- PH-C ----
    if (pf) {
#pragma unroll
      for (int jj = 0; jj < 2; jj++) {             // prefetch b0(t+1); bf0 dead after q10
        bf0[jj][0] = *(const short8*)&Bs[b ^ 1][0][bro + jj * 4096 + kc0];
        bf0[jj][1] = *(const short8*)&Bs[b ^ 1][0][bro + jj * 4096 + kc1];
      }
      SCHED0();
    }
    __builtin_amdgcn_s_setprio(1);
#pragma unroll
    for (int ks = 0; ks < 2; ks++)
#pragma unroll
      for (int i = 0; i < 4; i++)
#pragma unroll
        for (int jj = 0; jj < 2; jj++)
          acc[4 + i][2 + jj] = mfma16(af[i][ks], bf1[jj][ks], acc[4 + i][2 + jj]);
    __builtin_amdgcn_s_setprio(0);
  }
#undef STG
#undef BARR
#undef SCHED0
  // epilogue: C row = m0 + mf*32 + wm*16 + quad*4 + r; col = n0 + nf*64 + wn*16 + l16
#pragma unroll
  for (int nf = 0; nf < 4; nf++) {
    int col = n0 + nf * 64 + wn * 16 + l16;
    float bv = bias[col];
#pragma unroll
    for (int mf = 0; mf < 8; mf++) {
#pragma unroll
      for (int r = 0; r < 4; r++) {
        int row = m0 + mf * 32 + wm * 16 + quad * 4 + r;
        float v = acc[mf][nf][r] + bv;
        if (OUT_F32) ((float*)C)[(size_t)row * N + col] = v;
        else         ((u16*)C)[(size_t)row * N + col] = f2bf(v);
      }
    }
  }
}

// ---------- flash attention v6: 64-key tiles, double-buffered single-barrier ----------
__global__ __launch_bounds__(256, 2) void attn_kernel(
    const u16* __restrict__ Qp, const u16* __restrict__ Kp,
    const u16* __restrict__ Vt, u16* __restrict__ O) {
  __shared__ u16 Ks[2][64 * 104];   // 26.6 KB
  __shared__ u16 Vs[2][86 * 72];    // 24.2 KB
  __shared__ u16 Ps[4][16 * 72];    //  9.2 KB, per-wave (reused across mt)
  const int bid = blockIdx.x;
  const int phi = bid & 7, qt = (bid >> 3) & 7, pj = bid >> 6;
  const int p = pj * 8 + phi;       // (g,h) pair; its 8 qt-blocks share XCD
  const int g = p >> 4, h = p & 15;
  const int tid = threadIdx.x;
  const int w = tid >> 6, lane = tid & 63;
  const int quad = lane >> 4, l16 = lane & 15;

  short8 aq[2][3];
  const size_t qbase = ((size_t)(g * LSEG + qt * 128 + w * 32 + l16)) * 1536 + h * 96;
#pragma unroll
  for (int mt = 0; mt < 2; mt++)
#pragma unroll
    for (int ks = 0; ks < 3; ks++)
      aq[mt][ks] = *(const short8*)&Qp[qbase + (size_t)mt * 16 * 1536 + ks * 32 + quad * 8];

  const u16* gp[7]; u16* lp0[7]; u16* lp1[7]; int stp[7]; bool act[7];
#pragma unroll
  for (int i = 0; i < 7; i++) {
    int c = w + 4 * i;
    act[i] = (c < 25);
    int cc = act[i] ? c : 0;
    if (cc < 13) {                      // K: LDS elem = key*104 + rc*8
      int idx = cc * 64 + lane;
      int key = idx / 13, rc = idx % 13;
      int col = rc * 8; if (col >= 96) col = 0;
      gp[i] = Kp + (size_t)(g * LSEG + key) * 1536 + h * 96 + col;
      stp[i] = 64 * 1536;
      lp0[i] = &Ks[0][cc * 512]; lp1[i] = &Ks[1][cc * 512];
    } else {                            // V: LDS elem = d*72 + rc*8
      int cv = cc - 13;
      int idx = cv * 64 + lane;
      int d = idx / 9, rc = idx % 9;
      int col = rc * 8; if (col >= 64) col = 0;
      if (d >= 80) d = 0;
      gp[i] = Vt + (size_t)(h * 80 + d) * S + g * LSEG + col;
      stp[i] = 64;
      lp0[i] = &Vs[0][cv * 512]; lp1[i] = &Vs[1][cv * 512];
    }
  }
#pragma unroll
  for (int i = 0; i < 7; i++)
    if (act[i]) { glds16(gp[i], lp0[i]); gp[i] += stp[i]; }

  f32x4 o[2][5] = {};
  float lr[2][4] = {};
  u16* psw = &Ps[w][0];

  for (int kb = 0; kb < LSEG / 64; kb++) {
    const int b = kb & 1;
    __syncthreads();                    // drains prefetch of buf b (hidden by prior compute)
    if (kb < LSEG / 64 - 1) {           // prefetch next tile into buf b^1
      if (b == 0) {
#pragma unroll
        for (int i = 0; i < 7; i++)
          if (act[i]) { glds16(gp[i], lp1[i]); gp[i] += stp[i]; }
      } else {
#pragma unroll
        for (int i = 0; i < 7; i++)
          if (act[i]) { glds16(gp[i], lp0[i]); gp[i] += stp[i]; }
      }
    }
    f32x4 s[2][4] = {};
#pragma unroll
    for (int ks = 0; ks < 3; ks++) {
      short8 bk[4];
#pragma unroll
      for (int nt = 0; nt < 4; nt++)
        bk[nt] = *(const short8*)&Ks[b][(nt * 16 + l16) * 104 + ks * 32 + quad * 8];
#pragma unroll
      for (int mt = 0; mt < 2; mt++)
#pragma unroll
        for (int nt = 0; nt < 4; nt++)
          s[mt][nt] = mfma16(aq[mt][ks], bk[nt], s[mt][nt]);
    }
    short8 vb[5][2];
#pragma unroll
    for (int t = 0; t < 5; t++)
#pragma unroll
      for (int u = 0; u < 2; u++)
        vb[t][u] = *(const short8*)&Vs[b][(t * 16 + l16) * 72 + u * 32 + quad * 8];
#pragma unroll
    for (int mt = 0; mt < 2; mt++) {
#pragma unroll
      for (int r = 0; r < 4; r++) {
        float p0 = __builtin_amdgcn_exp2f(s[mt][0][r]);
        float p1 = __builtin_amdgcn_exp2f(s[mt][1][r]);
        float p2 = __builtin_amdgcn_exp2f(s[mt][2][r]);
        float p3 = __builtin_amdgcn_exp2f(s[mt][3][r]);
        lr[mt][r] += (p0 + p1) + (p2 + p3);
        int row = quad * 4 + r;
        uint2 pk; pk.x = pkbf(p0, p1); pk.y = pkbf(p2, p3);
        *(uint2*)&psw[row * 72 + l16 * 4] = pk;   // permuted cols: pp = l16*4 + nt
      }
      short8 pa0 = *(const short8*)&psw[l16 * 72 + quad * 8];
      short8 pa1 = *(const short8*)&psw[l16 * 72 + 32 + quad * 8];
#pragma unroll
      for (int t = 0; t < 5; t++)
        o[mt][t] = mfma16(pa0, vb[t][0], o[mt][t]);
#pragma unroll
      for (int t = 0; t < 5; t++)
        o[mt][t] = mfma16(pa1, vb[t][1], o[mt][t]);
    }
  }
#pragma unroll
  for (int mt = 0; mt < 2; mt++)
#pragma unroll
    for (int r = 0; r < 4; r++) {
      float t = lr[mt][r];
#pragma unroll
      for (int off = 8; off >= 1; off >>= 1) t += __shfl_xor(t, off, 16);
      float inv = 1.f / t;
      int srow = g * LSEG + qt * 128 + w * 32 + mt * 16 + quad * 4 + r;
#pragma unroll
      for (int tt = 0; tt < 5; tt++)
        O[(size_t)srow * DIM + h * DH + tt * 16 + l16] = f2bf(o[mt][tt][r] * inv);
    }
}

extern "C" void kernel_launch(void* const* d_in, const int* in_sizes, int n_in,
                              void* d_out, int out_size, void* d_ws, size_t ws_size,
                              hipStream_t stream) {
  const float* X     = (const float*)d_in[0];
  const float* cosp  = (const float*)d_in[1];
  const float* sinp  = (const float*)d_in[2];
  const float* qkvw  = (const float*)d_in[3];
  const float* qkvb  = (const float*)d_in[4];
  const float* projw = (const float*)d_in[5];
  const float* projb = (const float*)d_in[6];
  float* out = (float*)d_out;

  // workspace layout (u16 elems), ~143 MB total with aliasing:
  u16* Xb   = (u16*)d_ws;                     // 10,485,760  (dead after QKV gemm)
  u16* Wqb  = Xb   + (size_t)S * DIM;         //  4,915,200  (dead after QKV gemm)
  u16* Wpb  = Wqb  + (size_t)QKVN * DIM;      //  1,638,400  (live till proj)
  u16* QKVb = Wpb  + (size_t)DIM * DIM;       // 31,457,280  (dead after rope+vtrans)
  u16* Kp   = QKVb + (size_t)S * QKVN;        // 12,582,912
  u16* Vt   = Kp   + (size_t)S * H * 96;      // 10,485,760
  u16* Qp   = Xb;                             // alias: 12,582,912 <= Xb+Wqb region
  u16* AOb  = QKVb;                           // alias: 10,485,760 <= QKVb region

  cvt_kernel<<<16640, 256, 0, stream>>>(X, qkvw, projw, Xb, Wqb, Wpb);
  gemm_bt<false><<<(S / 256) * (QKVN / 256), 512, 0, stream>>>(Xb, Wqb, qkvb, QKVb, DIM, QKVN);
  rope_kernel<<<(S * H * 5) / 256, 256, 0, stream>>>(QKVb, cosp, sinp, Qp, Kp);
  vtrans_kernel<<<dim3(S / 64, H), 256, 0, stream>>>(QKVb, Vt);
  attn_kernel<<<1024, 256, 0, stream>>>(Qp, Kp, Vt, AOb);
  gemm_bt<true><<<(S / 256) * (DIM / 256), 512, 0, stream>>>(AOb, Wpb, projb, out, DIM, DIM);
}

// Round 8
// 321.821 us; speedup vs baseline: 1.0752x; 1.0105x over previous
//
#include <hip/hip_runtime.h>
#include <hip/hip_bf16.h>
#include <stdint.h>

typedef unsigned short u16;
typedef unsigned int u32;
typedef __attribute__((ext_vector_type(8))) short short8;  // 8 x bf16 (4 VGPRs)
typedef __attribute__((ext_vector_type(4))) float f32x4;

#define DEV __device__ __forceinline__

constexpr int S = 8192;
constexpr int DIM = 1280;
constexpr int H = 16;
constexpr int DH = 80;
constexpr int LSEG = 1024;      // uniform segment length (cu_seqlens = arange*1024)
constexpr int QKVN = 3 * DIM;   // 3840
// 80^-0.5 * log2(e): scores then feed exp2 directly (softmax invariant)
constexpr float SCALE = 0.11180339887498949f * 1.4426950408889634f;

DEV u16 f2bf(float f) {
  u32 u = __float_as_uint(f);
  return (u16)((u + 0x7FFFu + ((u >> 16) & 1u)) >> 16);  // round-to-nearest-even
}
DEV float bf2f(u16 h) { return __uint_as_float(((u32)h) << 16); }
DEV u32 pkbf(float a, float b) {       // v_cvt_pk_bf16_f32
  __hip_bfloat162 t = __float22bfloat162_rn(float2{a, b});
  u32 r; __builtin_memcpy(&r, &t, 4); return r;
}

DEV void glds16(const void* g, void* l) {
  __builtin_amdgcn_global_load_lds((__attribute__((address_space(1))) void*)g,
                                   (__attribute__((address_space(3))) void*)l,
                                   16, 0, 0);
}
DEV f32x4 mfma16(short8 a, short8 b, f32x4 c) {
  return __builtin_amdgcn_mfma_f32_16x16x32_bf16(a, b, c, 0, 0, 0);
}

// ---------- fp32 -> bf16 conversion of X, qkv_w, proj_w ----------
__global__ __launch_bounds__(256) void cvt_kernel(
    const float* __restrict__ X, const float* __restrict__ Wq,
    const float* __restrict__ Wp, u16* __restrict__ Xb,
    u16* __restrict__ Wqb, u16* __restrict__ Wpb) {
  size_t i = ((size_t)blockIdx.x * 256 + threadIdx.x) * 4;
  const size_t n1 = (size_t)S * DIM;      // 10485760
  const size_t n2 = (size_t)QKVN * DIM;   // 4915200
  const size_t n3 = (size_t)DIM * DIM;    // 1638400
  const float* src; u16* dst; size_t off;
  if (i < n1)                { src = X;  dst = Xb;  off = i; }
  else if (i < n1 + n2)      { src = Wq; dst = Wqb; off = i - n1; }
  else if (i < n1 + n2 + n3) { src = Wp; dst = Wpb; off = i - n1 - n2; }
  else return;
  float4 v = *(const float4*)(src + off);
  ushort4 r;
  r.x = f2bf(v.x); r.y = f2bf(v.y); r.z = f2bf(v.z); r.w = f2bf(v.w);
  *(ushort4*)(dst + off) = r;
}

// ---------- RoPE v2 (vectorized): QKV[s][3840] -> Qp[s][h][96], Kp[s][h][96] ----------
__global__ __launch_bounds__(256) void rope_kernel(
    const u16* __restrict__ QKV, const float* __restrict__ cosp,
    const float* __restrict__ sinp, u16* __restrict__ Qp, u16* __restrict__ Kp) {
  int idx = blockIdx.x * 256 + threadIdx.x;   // over S*H*5 exactly
  int c = idx % 5;
  int sh = idx / 5;
  int s = sh >> 4, h = sh & 15;
  const size_t gbase = (size_t)s * QKVN + h * DH + c * 8;
  const size_t pbase = (size_t)sh * 96 + c * 8;
  short8 q0 = *(const short8*)&QKV[gbase];
  short8 q1 = *(const short8*)&QKV[gbase + 40];
  short8 k0 = *(const short8*)&QKV[gbase + DIM];
  short8 k1 = *(const short8*)&QKV[gbase + DIM + 40];
  float4 ca0 = *(const float4*)&cosp[s * DH + c * 8];
  float4 ca1 = *(const float4*)&cosp[s * DH + c * 8 + 4];
  float4 cb0 = *(const float4*)&cosp[s * DH + c * 8 + 40];
  float4 cb1 = *(const float4*)&cosp[s * DH + c * 8 + 44];
  float4 sa0 = *(const float4*)&sinp[s * DH + c * 8];
  float4 sa1 = *(const float4*)&sinp[s * DH + c * 8 + 4];
  float4 sb0 = *(const float4*)&sinp[s * DH + c * 8 + 40];
  float4 sb1 = *(const float4*)&sinp[s * DH + c * 8 + 44];
  float ca[8] = {ca0.x, ca0.y, ca0.z, ca0.w, ca1.x, ca1.y, ca1.z, ca1.w};
  float cb[8] = {cb0.x, cb0.y, cb0.z, cb0.w, cb1.x, cb1.y, cb1.z, cb1.w};
  float sa[8] = {sa0.x, sa0.y, sa0.z, sa0.w, sa1.x, sa1.y, sa1.z, sa1.w};
  float sb[8] = {sb0.x, sb0.y, sb0.z, sb0.w, sb1.x, sb1.y, sb1.z, sb1.w};
  short8 qo0, qo1, ko0, ko1;
#pragma unroll
  for (int j = 0; j < 8; j++) {
    float qa = bf2f((u16)q0[j]), qb = bf2f((u16)q1[j]);
    float ka = bf2f((u16)k0[j]), kb = bf2f((u16)k1[j]);
    qo0[j] = (short)f2bf((qa * ca[j] - qb * sa[j]) * SCALE);
    qo1[j] = (short)f2bf((qb * cb[j] + qa * sb[j]) * SCALE);
    ko0[j] = (short)f2bf(ka * ca[j] - kb * sa[j]);
    ko1[j] = (short)f2bf(kb * cb[j] + ka * sb[j]);
  }
  *(short8*)&Qp[pbase]      = qo0;
  *(short8*)&Qp[pbase + 40] = qo1;
  *(short8*)&Kp[pbase]      = ko0;
  *(short8*)&Kp[pbase + 40] = ko1;
  if (c == 0) {                          // zero pads d=80..95
    short8 z = {};
    *(short8*)&Qp[pbase + 80] = z; *(short8*)&Qp[pbase + 88] = z;
    *(short8*)&Kp[pbase + 80] = z; *(short8*)&Kp[pbase + 88] = z;
  }
}

// ---------- V transpose + per-64 permute ----------
__global__ __launch_bounds__(256) void vtrans_kernel(
    const u16* __restrict__ QKV, u16* __restrict__ Vt) {
  __shared__ u16 Ls[64 * 88];             // 64 rows x 80 d, stride 88 (16B-aligned)
  const int s0 = blockIdx.x * 64, h = blockIdx.y;
  const int tid = threadIdx.x;
  for (int cc = tid; cc < 640; cc += 256) {   // 64 rows x 10 chunks of 8 elems
    int row = cc / 10, c = cc % 10;
    short8 v = *(const short8*)&QKV[(size_t)(s0 + row) * QKVN + 2 * DIM + h * 80 + c * 8];
    *(short8*)&Ls[row * 88 + c * 8] = v;
  }
  __syncthreads();
  for (int cc = tid; cc < 640; cc += 256) {   // 80 d-rows x 8 chunks of 8 out-pos
    int d = cc / 8, sc = cc % 8;
    u16 tmp[8];
#pragma unroll
    for (int j = 0; j < 8; j++) {
      int op = sc * 8 + j;
      int key = ((op & 3) << 4) + (op >> 2);  // inverse of pp()
      tmp[j] = Ls[key * 88 + d];
    }
    *(short8*)&Vt[(size_t)(h * 80 + d) * S + s0 + sc * 8] = *(short8*)tmp;
  }
}

// ---------- GEMM v10: v9 + FULL register rotation (all ds_reads in MFMA shadow) ----
// v9's one remaining exposed block: PH-A opened with 12 unshadowed ds_reads (a0+b1).
// v10 rotates af in PH-C (af[i] <- Ah0(t+1) after af[i]'s last q11 MFMA; legal:
// As[b^1][0] published at BAR#2 which precedes PH-C; reg-WAR orders reads).
// PH-A shrinks to 4 bf1 reads.  Zero new registers.
// FIFO/publication (per tile t, buf b=t&1; STG = 2 glds):
//   PH-A: read bf1<-Bs[b][1] | STG Ah0,Bh0(t+1)->[b^1][0] | lgkm(4): rotation(12)
//         drained (shadowed by q11(t-1)) | q00 | vmcnt(4): Ah1(t) landed | BAR#1
//   PH-B: lgkm(0): bf1 (under q00) | STG Bh1(t+1) | q01 + af[i]<-As[b][1] rotation
//         | STG Ah1(t+1) | lgkm(0): a1 (under q01) | q10 | vmcnt(2): h0+Bh1(t+1)
//         landed | BAR#2 publishes them
//   PH-C: read bf0<-Bs[b^1][0] | q11 + af[i]<-As[b^1][0] rotation | (no barrier)
// Invariant entering t: outstanding glds = Ah1(t) x2; outstanding lgkm = 12
// rotation reads.  WAR pairs all sealed by the same barriers as v9 (PH-C touches
// only buf b^1 slots whose stages come after BAR#2; PH-A stages touch slots last
// read before BAR#2(t-1)).
template <bool OUT_F32>
__global__ __launch_bounds__(512, 2) void gemm_bt(
    const u16* __restrict__ A, const u16* __restrict__ B,
    const float* __restrict__ bias, void* __restrict__ C, int K, int N) {
  __shared__ u16 As[2][2][8192];   // [dbuf][half][128*64]
  __shared__ u16 Bs[2][2][8192];
  const int ntn = N >> 8;                       // n-tiles
  const int q = gridDim.x >> 3;                 // bijective XCD swizzle (nwg%8==0)
  const int widx = (blockIdx.x & 7) * q + (blockIdx.x >> 3);
  const int m0 = (widx / ntn) << 8;             // n-fastest: XCD works 1024-row A slab
  const int n0 = (widx % ntn) << 8;
  const int tid = threadIdx.x;
  const int w = tid >> 6, lane = tid & 63;
  const int quad = lane >> 4, l16 = lane & 15;
  const int wm = w >> 2, wn = w & 3;            // wave grid 2 x 4

  // staging: per half-tile (128 rows x 64 k) each wave does 2 glds16 (8 rows each).
  // LDS linear in write order; global source pre-swizzled: col-chunk = (lane&7)^(lane>>3)
  const int rowoff = w * 8 + (lane >> 3);
  const int coloff = ((lane & 7) ^ (lane >> 3)) * 8;
  const u16* pa0 = A + (size_t)(m0 + rowoff) * K + coloff;         // A half0 (rows 0..127)
  const u16* pa1 = A + (size_t)(m0 + 128 + rowoff) * K + coloff;   // A half1
  const u16* pb0 = B + (size_t)(n0 + rowoff) * K + coloff;
  const u16* pb1 = B + (size_t)(n0 + 128 + rowoff) * K + coloff;
  const size_t j64 = (size_t)64 * K;

#define STG(P, DST, kk) do { \
    glds16((P) + (kk), &(DST)[w * 512]); \
    glds16((P) + j64 + (kk), &(DST)[4096 + w * 512]); } while (0)
#define BARR()  __builtin_amdgcn_s_barrier()
#define SCHED0() __builtin_amdgcn_sched_barrier(0)

  // frag read addressing (row&7 == l16&7 for all frag rows)
  const int aro = (wm * 16 + l16) * 64;                 // + i*32*64
  const int bro = (wn * 16 + l16) * 64;                 // + j*64*64
  const int kc0 = ((quad) ^ (l16 & 7)) * 8;             // ks=0 swizzled chunk
  const int kc1 = ((4 + quad) ^ (l16 & 7)) * 8;         // ks=1

  f32x4 acc[8][4] = {};
  short8 af[4][2], bf0[2][2], bf1[2][2];
  const int NT = K >> 6;   // K-tiles (20 for K=1280)

  // prologue: stage tile0 [h0 x4, Bh1 x2, Ah1 x2]; drain h0+Bh1; publish;
  // preload rotation regs (bf0 + af = 12 reads, left in flight for PH-A's lgkm(4))
  STG(pa0, As[0][0], 0); STG(pb0, Bs[0][0], 0);
  STG(pb1, Bs[0][1], 0);
  STG(pa1, As[0][1], 0);
  asm volatile("s_waitcnt vmcnt(2)");
  BARR();
#pragma unroll
  for (int jj = 0; jj < 2; jj++) {
    bf0[jj][0] = *(const short8*)&Bs[0][0][bro + jj * 4096 + kc0];
    bf0[jj][1] = *(const short8*)&Bs[0][0][bro + jj * 4096 + kc1];
  }
#pragma unroll
  for (int i = 0; i < 4; i++) {
    af[i][0] = *(const short8*)&As[0][0][aro + i * 2048 + kc0];
    af[i][1] = *(const short8*)&As[0][0][aro + i * 2048 + kc1];
  }
  // entering loop: outstanding glds = [Ah1(0) x2]; lgkm = 12 rotation reads

  for (int t = 0; t < NT; ++t) {
    const int b = t & 1;
    const int kk = (t + 1) << 6;
    const bool pf = (t + 1 < NT);
    // ---- PH-A: read bf1 (4); stage h0(t+1); lgkm(4); q00; vmcnt(4); BAR#1 ----
#pragma unroll
    for (int jj = 0; jj < 2; jj++) {
      bf1[jj][0] = *(const short8*)&Bs[b][1][bro + jj * 4096 + kc0];
      bf1[jj][1] = *(const short8*)&Bs[b][1][bro + jj * 4096 + kc1];
    }
    if (pf) { STG(pa0, As[b ^ 1][0], kk); STG(pb0, Bs[b ^ 1][0], kk); }
    asm volatile("s_waitcnt lgkmcnt(4)");   // rotation(12) drained; bf1(4) flying
    SCHED0();
    __builtin_amdgcn_s_setprio(1);
#pragma unroll
    for (int ks = 0; ks < 2; ks++)
#pragma unroll
      for (int i = 0; i < 4; i++)
#pragma unroll
        for (int jj = 0; jj < 2; jj++)
          acc[i][jj] = mfma16(af[i][ks], bf0[jj][ks], acc[i][jj]);
    __builtin_amdgcn_s_setprio(0);
    SCHED0();
    if (pf) asm volatile("s_waitcnt vmcnt(4)");   // Ah1(t) landed
    else    asm volatile("s_waitcnt vmcnt(0)");
    BARR();                                        // #1: publishes Ah1(t)
    // ---- PH-B: lgkm(0); stage Bh1; q01 + a1 rotation; stage Ah1; lgkm(0); q10;
    //            vmcnt(2); BAR#2 ----
    asm volatile("s_waitcnt lgkmcnt(0)");   // bf1 ready (drained under q00)
    SCHED0();
    if (pf) STG(pb1, Bs[b ^ 1][1], kk);
    __builtin_amdgcn_s_setprio(1);
#pragma unroll
    for (int i = 0; i < 4; i++) {
      // q01 MFMAs consuming a0[i], then overwrite af[i] with a1[i] (WAR orders read)
      acc[i][2] = mfma16(af[i][0], bf1[0][0], acc[i][2]);
      acc[i][3] = mfma16(af[i][0], bf1[1][0], acc[i][3]);
      acc[i][2] = mfma16(af[i][1], bf1[0][1], acc[i][2]);
      acc[i][3] = mfma16(af[i][1], bf1[1][1], acc[i][3]);
      af[i][0] = *(const short8*)&As[b][1][aro + i * 2048 + kc0];
      af[i][1] = *(const short8*)&As[b][1][aro + i * 2048 + kc1];
    }
    __builtin_amdgcn_s_setprio(0);
    if (pf) STG(pa1, As[b ^ 1][1], kk);
    asm volatile("s_waitcnt lgkmcnt(0)");   // a1 ready (drained under q01)
    SCHED0();
    __builtin_amdgcn_s_setprio(1);
#pragma unroll
    for (int ks = 0; ks < 2; ks++)
#pragma unroll
      for (int i = 0; i < 4; i++)
#pragma unroll
        for (int jj = 0; jj < 2; jj++)
          acc[4 + i][jj] = mfma16(af[i][ks], bf0[jj][ks], acc[4 + i][jj]);
    __builtin_amdgcn_s_setprio(0);
    SCHED0();
    if (pf) asm volatile("s_waitcnt vmcnt(2)");   // h0(t+1)+Bh1(t+1) landed
    else    asm volatile("s_waitcnt vmcnt(0)");
    BARR();                                        // #2: publishes h0/Bh1(t+1)
    // ---- PH-C: read bf0(t+1); q11 + a0(t+1) rotation; no barrier ----
    if (pf) {
#pragma unroll
      for (int jj = 0; jj < 2; jj++) {             // bf0 dead after q10
        bf0[jj][0] = *(const short8*)&Bs[b ^ 1][0][bro + jj * 4096 + kc0];
        bf0[jj][1] = *(const short8*)&Bs[b ^ 1][0][bro + jj * 4096 + kc1];
      }
      SCHED0();
      __builtin_amdgcn_s_setprio(1);
#pragma unroll
      for (int i = 0; i < 4; i++) {
        // q11 MFMAs consuming af[i] (=a1(t)), then rotate af[i] <- a0(t+1)
        acc[4 + i][2] = mfma16(af[i][0], bf1[0][0], acc[4 + i][2]);
        acc[4 + i][3] = mfma16(af[i][0], bf1[1][0], acc[4 + i][3]);
        acc[4 + i][2] = mfma16(af[i][1], bf1[0][1], acc[4 + i][2]);
        acc[4 + i][3] = mfma16(af[i][1], bf1[1][1], acc[4 + i][3]);
        af[i][0] = *(const short8*)&As[b ^ 1][0][aro + i * 2048 + kc0];
        af[i][1] = *(const short8*)&As[b ^ 1][0][aro + i * 2048 + kc1];
      }
      __builtin_amdgcn_s_setprio(0);
    } else {
      __builtin_amdgcn_s_setprio(1);
#pragma unroll
      for (int ks = 0; ks < 2; ks++)
#pragma unroll
        for (int i = 0; i < 4; i++)
#pragma unroll
          for (int jj = 0; jj < 2; jj++)
            acc[4 + i][2 + jj] = mfma16(af[i][ks], bf1[jj][ks], acc[4 + i][2 + jj]);
      __builtin_amdgcn_s_setprio(0);
    }
  }
#undef STG
#undef BARR
#undef SCHED0
  // epilogue: C row = m0 + mf*32 + wm*16 + quad*4 + r; col = n0 + nf*64 + wn*16 + l16
#pragma unroll
  for (int nf = 0; nf < 4; nf++) {
    int col = n0 + nf * 64 + wn * 16 + l16;
    float bv = bias[col];
#pragma unroll
    for (int mf = 0; mf < 8; mf++) {
#pragma unroll
      for (int r = 0; r < 4; r++) {
        int row = m0 + mf * 32 + wm * 16 + quad * 4 + r;
        float v = acc[mf][nf][r] + bv;
        if (OUT_F32) ((float*)C)[(size_t)row * N + col] = v;
        else         ((u16*)C)[(size_t)row * N + col] = f2bf(v);
      }
    }
  }
}

// ---------- flash attention v6: 64-key tiles, double-buffered single-barrier ----------
__global__ __launch_bounds__(256, 2) void attn_kernel(
    const u16* __restrict__ Qp, const u16* __restrict__ Kp,
    const u16* __restrict__ Vt, u16* __restrict__ O) {
  __shared__ u16 Ks[2][64 * 104];   // 26.6 KB
  __shared__ u16 Vs[2][86 * 72];    // 24.2 KB
  __shared__ u16 Ps[4][16 * 72];    //  9.2 KB, per-wave (reused across mt)
  const int bid = blockIdx.x;
  const int phi = bid & 7, qt = (bid >> 3) & 7, pj = bid >> 6;
  const int p = pj * 8 + phi;       // (g,h) pair; its 8 qt-blocks share XCD
  const int g = p >> 4, h = p & 15;
  const int tid = threadIdx.x;
  const int w = tid >> 6, lane = tid & 63;
  const int quad = lane >> 4, l16 = lane & 15;

  short8 aq[2][3];
  const size_t qbase = ((size_t)(g * LSEG + qt * 128 + w * 32 + l16)) * 1536 + h * 96;
#pragma unroll
  for (int mt = 0; mt < 2; mt++)
#pragma unroll
    for (int ks = 0; ks < 3; ks++)
      aq[mt][ks] = *(const short8*)&Qp[qbase + (size_t)mt * 16 * 1536 + ks * 32 + quad * 8];

  const u16* gp[7]; u16* lp0[7]; u16* lp1[7]; int stp[7]; bool act[7];
#pragma unroll
  for (int i = 0; i < 7; i++) {
    int c = w + 4 * i;
    act[i] = (c < 25);
    int cc = act[i] ? c : 0;
    if (cc < 13) {                      // K: LDS elem = key*104 + rc*8
      int idx = cc * 64 + lane;
      int key = idx / 13, rc = idx % 13;
      int col = rc * 8; if (col >= 96) col = 0;
      gp[i] = Kp + (size_t)(g * LSEG + key) * 1536 + h * 96 + col;
      stp[i] = 64 * 1536;
      lp0[i] = &Ks[0][cc * 512]; lp1[i] = &Ks[1][cc * 512];
    } else {                            // V: LDS elem = d*72 + rc*8
      int cv = cc - 13;
      int idx = cv * 64 + lane;
      int d = idx / 9, rc = idx % 9;
      int col = rc * 8; if (col >= 64) col = 0;
      if (d >= 80) d = 0;
      gp[i] = Vt + (size_t)(h * 80 + d) * S + g * LSEG + col;
      stp[i] = 64;
      lp0[i] = &Vs[0][cv * 512]; lp1[i] = &Vs[1][cv * 512];
    }
  }
#pragma unroll
  for (int i = 0; i < 7; i++)
    if (act[i]) { glds16(gp[i], lp0[i]); gp[i] += stp[i]; }

  f32x4 o[2][5] = {};
  float lr[2][4] = {};
  u16* psw = &Ps[w][0];

  for (int kb = 0; kb < LSEG / 64; kb++) {
    const int b = kb & 1;
    __syncthreads();                    // drains prefetch of buf b (hidden by prior compute)
    if (kb < LSEG / 64 - 1) {           // prefetch next tile into buf b^1
      if (b == 0) {
#pragma unroll
        for (int i = 0; i < 7; i++)
          if (act[i]) { glds16(gp[i], lp1[i]); gp[i] += stp[i]; }
      } else {
#pragma unroll
        for (int i = 0; i < 7; i++)
          if (act[i]) { glds16(gp[i], lp0[i]); gp[i] += stp[i]; }
      }
    }
    f32x4 s[2][4] = {};
#pragma unroll
    for (int ks = 0; ks < 3; ks++) {
      short8 bk[4];
#pragma unroll
      for (int nt = 0; nt < 4; nt++)
        bk[nt] = *(const short8*)&Ks[b][(nt * 16 + l16) * 104 + ks * 32 + quad * 8];
#pragma unroll
      for (int mt = 0; mt < 2; mt++)
#pragma unroll
        for (int nt = 0; nt < 4; nt++)
          s[mt][nt] = mfma16(aq[mt][ks], bk[nt], s[mt][nt]);
    }
    short8 vb[5][2];
#pragma unroll
    for (int t = 0; t < 5; t++)
#pragma unroll
      for (int u = 0; u < 2; u++)
        vb[t][u] = *(const short8*)&Vs[b][(t * 16 + l16) * 72 + u * 32 + quad * 8];
#pragma unroll
    for (int mt = 0; mt < 2; mt++) {
#pragma unroll
      for (int r = 0; r < 4; r++) {
        float p0 = __builtin_amdgcn_exp2f(s[mt][0][r]);
        float p1 = __builtin_amdgcn_exp2f(s[mt][1][r]);
        float p2 = __builtin_amdgcn_exp2f(s[mt][2][r]);
        float p3 = __builtin_amdgcn_exp2f(s[mt][3][r]);
        lr[mt][r] += (p0 + p1) + (p2 + p3);
        int row = quad * 4 + r;
        uint2 pk; pk.x = pkbf(p0, p1); pk.y = pkbf(p2, p3);
        *(uint2*)&psw[row * 72 + l16 * 4] = pk;   // permuted cols: pp = l16*4 + nt
      }
      short8 pa0 = *(const short8*)&psw[l16 * 72 + quad * 8];
      short8 pa1 = *(const short8*)&psw[l16 * 72 + 32 + quad * 8];
#pragma unroll
      for (int t = 0; t < 5; t++)
        o[mt][t] = mfma16(pa0, vb[t][0], o[mt][t]);
#pragma unroll
      for (int t = 0; t < 5; t++)
        o[mt][t] = mfma16(pa1, vb[t][1], o[mt][t]);
    }
  }
#pragma unroll
  for (int mt = 0; mt < 2; mt++)
#pragma unroll
    for (int r = 0; r < 4; r++) {
      float t = lr[mt][r];
#pragma unroll
      for (int off = 8; off >= 1; off >>= 1) t += __shfl_xor(t, off, 16);
      float inv = 1.f / t;
      int srow = g * LSEG + qt * 128 + w * 32 + mt * 16 + quad * 4 + r;
#pragma unroll
      for (int tt = 0; tt < 5; tt++)
        O[(size_t)srow * DIM + h * DH + tt * 16 + l16] = f2bf(o[mt][tt][r] * inv);
    }
}

extern "C" void kernel_launch(void* const* d_in, const int* in_sizes, int n_in,
                              void* d_out, int out_size, void* d_ws, size_t ws_size,
                              hipStream_t stream) {
  const float* X     = (const float*)d_in[0];
  const float* cosp  = (const float*)d_in[1];
  const float* sinp  = (const float*)d_in[2];
  const float* qkvw  = (const float*)d_in[3];
  const float* qkvb  = (const float*)d_in[4];
  const float* projw = (const float*)d_in[5];
  const float* projb = (const float*)d_in[6];
  float* out = (float*)d_out;

  // workspace layout (u16 elems), ~143 MB total with aliasing:
  u16* Xb   = (u16*)d_ws;                     // 10,485,760  (dead after QKV gemm)
  u16* Wqb  = Xb   + (size_t)S * DIM;         //  4,915,200  (dead after QKV gemm)
  u16* Wpb  = Wqb  + (size_t)QKVN * DIM;      //  1,638,400  (live till proj)
  u16* QKVb = Wpb  + (size_t)DIM * DIM;       // 31,457,280  (dead after rope+vtrans)
  u16* Kp   = QKVb + (size_t)S * QKVN;        // 12,582,912
  u16* Vt   = Kp   + (size_t)S * H * 96;      // 10,485,760
  u16* Qp   = Xb;                             // alias: 12,582,912 <= Xb+Wqb region
  u16* AOb  = QKVb;                           // alias: 10,485,760 <= QKVb region

  cvt_kernel<<<16640, 256, 0, stream>>>(X, qkvw, projw, Xb, Wqb, Wpb);
  gemm_bt<false><<<(S / 256) * (QKVN / 256), 512, 0, stream>>>(Xb, Wqb, qkvb, QKVb, DIM, QKVN);
  rope_kernel<<<(S * H * 5) / 256, 256, 0, stream>>>(QKVb, cosp, sinp, Qp, Kp);
  vtrans_kernel<<<dim3(S / 64, H), 256, 0, stream>>>(QKVb, Vt);
  attn_kernel<<<1024, 256, 0, stream>>>(Qp, Kp, Vt, AOb);
  gemm_bt<true><<<(S / 256) * (DIM / 256), 512, 0, stream>>>(AOb, Wpb, projb, out, DIM, DIM);
}